// Round 1
// baseline (92095.276 us; speedup 1.0000x reference)
//
#include <hip/hip_runtime.h>
#include <stdint.h>

#define HH 640
#define BB 128
#define TT 512
#define VV 4097
#define G4 2560   // 4*HH

__device__ __forceinline__ float sigm(float x){ return 1.0f/(1.0f+expf(-x)); }

// monotonic packed key: larger logit wins; ties -> smaller v wins (matches jnp.argmax first-index)
__device__ __forceinline__ unsigned long long packkey(float f, unsigned v){
    unsigned u = __float_as_uint(f);
    unsigned m = (u & 0x80000000u) ? ~u : (u | 0x80000000u);
    return ((unsigned long long)m << 32) | (unsigned long long)(~v);
}

// bijective XCD partition: consecutive tiles-in-xcd -> contiguous tile range per XCD
__device__ __forceinline__ int xcd_tile(int bid, int per){ return (bid & 7)*per + (bid >> 3); }

// ---------------- init ----------------
__global__ __launch_bounds__(256) void k_init(const float* __restrict__ h0, const float* __restrict__ c0,
                       float* __restrict__ hs0, float* __restrict__ cs,
                       int* __restrict__ label, unsigned long long* __restrict__ slot){
    int i = blockIdx.x*256 + threadIdx.x;
    if (i < BB*HH){ hs0[i] = h0[i]; cs[i] = c0[i]; }
    if (i < BB){ label[i] = 0; slot[i] = 0ULL; }
}

// ---------------- emb_proj precompute: [VV+1][2560]; row VV = bias-only ----------------
__global__ __launch_bounds__(256) void k_embproj(const float* __restrict__ embedding,
                          const float* __restrict__ Wih,
                          const float* __restrict__ b_ih, const float* __restrict__ b_hh,
                          float* __restrict__ embproj){
    int tile = xcd_tile(blockIdx.x, 322);
    if (tile >= 2570) return;
    int ut = tile / 257;        // 0..9
    int vg = tile % 257;        // 16 v-rows per group
    int u  = ut*256 + threadIdx.x;
    float acc[16];
    #pragma unroll
    for (int i=0;i<16;i++) acc[i]=0.f;
    const float* wr = Wih + (size_t)u*HH;
    for (int kc=0; kc<HH; kc+=16){
        float wv[16];
        #pragma unroll
        for (int q=0;q<4;q++){
            float4 f = *reinterpret_cast<const float4*>(wr + kc + q*4);
            wv[q*4+0]=f.x; wv[q*4+1]=f.y; wv[q*4+2]=f.z; wv[q*4+3]=f.w;
        }
        #pragma unroll
        for (int vi=0; vi<16; ++vi){
            int v = vg*16+vi;
            if (v < VV){
                const float* ep = embedding + (size_t)v*HH + kc;
                float a = acc[vi];
                #pragma unroll
                for (int k=0;k<16;k++) a = fmaf(ep[k], wv[k], a);
                acc[vi] = a;
            }
        }
    }
    float bias = b_ih[u] + b_hh[u];
    #pragma unroll
    for (int vi=0; vi<16; ++vi){
        int v = vg*16+vi;
        if (v <= VV) embproj[(size_t)v*G4 + u] = acc[vi] + bias;
    }
}

// ---------------- enc_proj precompute: out[t][b][n] = x[b,:,t].W_enc[n,:] + b_enc[n] ----------------
__global__ __launch_bounds__(128) void k_encproj(const float* __restrict__ x,
                          const float* __restrict__ Wenc, const float* __restrict__ b_enc,
                          float* __restrict__ encproj){
    int tile = xcd_tile(blockIdx.x, 2560);      // 20480 total
    int b   = tile / 160;
    int rem = tile % 160;
    int tt  = rem / 5;                          // 16-t tile
    int nt2 = rem % 5;
    int lane = threadIdx.x & 63, w = threadIdx.x >> 6;
    int n = nt2*128 + w*64 + lane;
    float acc[16];
    #pragma unroll
    for (int i=0;i<16;i++) acc[i]=0.f;
    const float* wr = Wenc + (size_t)n*HH;
    for (int kc=0; kc<HH; kc+=16){
        float wv[16];
        #pragma unroll
        for (int q=0;q<4;q++){
            float4 f = *reinterpret_cast<const float4*>(wr + kc + q*4);
            wv[q*4+0]=f.x; wv[q*4+1]=f.y; wv[q*4+2]=f.z; wv[q*4+3]=f.w;
        }
        #pragma unroll
        for (int k=0;k<16;k++){
            const float* xp = x + (size_t)b*HH*TT + (size_t)(kc+k)*TT + tt*16;  // uniform, 16 consecutive
            float ww = wv[k];
            #pragma unroll
            for (int ti=0; ti<16; ++ti) acc[ti] = fmaf(xp[ti], ww, acc[ti]);
        }
    }
    float be = b_enc[n];
    #pragma unroll
    for (int ti=0; ti<16; ++ti)
        encproj[(size_t)(tt*16+ti)*BB*HH + (size_t)b*HH + n] = acc[ti] + be;
}

// ---------------- P1: gates GEMM + LSTM nonlin + lazy commit of step t-1 ----------------
template<int HAS_EMB>
__global__ __launch_bounds__(256) void k_p1(
    const float* __restrict__ Whh,
    const float* __restrict__ Wih,
    const float* __restrict__ embproj,
    const float* __restrict__ embedding,
    const float* __restrict__ b_ih, const float* __restrict__ b_hh,
    const int*   __restrict__ lens,
    const float* __restrict__ hs_r, float* __restrict__ hs_w,
    const float* __restrict__ h1_r, float* __restrict__ h1_w,
    float* c_state, float* c1,
    int*   label,
    const unsigned long long* __restrict__ slot,
    float* __restrict__ out_emit,
    int t)
{
    int tile = xcd_tile(blockIdx.x, 20);   // 160 tiles = 10 jt x 16 bg
    int jt = tile >> 4;
    int bg = tile & 15;
    int lane = threadIdx.x & 63;
    int w    = threadIdx.x >> 6;           // gate index 0..3
    int j  = (jt<<6) + lane;
    int b0 = bg<<3;

    bool mask[8]; int kprev[8]; int sel[8];
    #pragma unroll
    for (int bi=0; bi<8; ++bi){
        int b = b0+bi;
        if (t == 0){ mask[bi]=true; sel[bi]=0; kprev[bi]=0; }
        else {
            unsigned long long key = slot[b];
            int k = (int)(~(unsigned)key);
            int lab = label[b];
            bool m = ((t-1) >= lens[b]) || (k == 0);
            mask[bi]=m; kprev[bi]=k; sel[bi] = m ? lab : k;
        }
    }

    float acc[8];
    #pragma unroll
    for (int i=0;i<8;i++) acc[i]=0.f;

    const float* wrow  = Whh + (size_t)(w*HH + j)*HH;
    const float* wrow2 = Wih + (size_t)(w*HH + j)*HH;

    for (int kc=0; kc<HH; kc+=16){
        float wv[16];
        #pragma unroll
        for (int q=0;q<4;q++){
            float4 f = *reinterpret_cast<const float4*>(wrow + kc + q*4);
            wv[q*4+0]=f.x; wv[q*4+1]=f.y; wv[q*4+2]=f.z; wv[q*4+3]=f.w;
        }
        float wv2[16];
        if (!HAS_EMB){
            #pragma unroll
            for (int q=0;q<4;q++){
                float4 f = *reinterpret_cast<const float4*>(wrow2 + kc + q*4);
                wv2[q*4+0]=f.x; wv2[q*4+1]=f.y; wv2[q*4+2]=f.z; wv2[q*4+3]=f.w;
            }
        }
        #pragma unroll
        for (int bi=0; bi<8; ++bi){
            int b = b0+bi;
            const float* hp0 = hs_r + (size_t)b*HH + kc;
            const float* hp1 = h1_r + (size_t)b*HH + kc;
            float a = acc[bi];
            if (mask[bi]){                         // block-uniform branch
                #pragma unroll
                for (int k=0;k<16;k++) a = fmaf(hp0[k], wv[k], a);
            } else {
                #pragma unroll
                for (int k=0;k<16;k++) a = fmaf(hp1[k], wv[k], a);
            }
            if (!HAS_EMB){
                if (t > 0){
                    const float* ep = embedding + (size_t)sel[bi]*HH + kc;
                    #pragma unroll
                    for (int k=0;k<16;k++) a = fmaf(ep[k], wv2[k], a);
                }
            }
            acc[bi] = a;
        }
    }

    __shared__ float xch[8][4][64];
    #pragma unroll
    for (int bi=0; bi<8; ++bi){
        float g = acc[bi];
        if (HAS_EMB){
            int row = (t==0) ? VV : sel[bi];
            g += embproj[(size_t)row*G4 + w*HH + j];
        } else {
            g += b_ih[w*HH + j] + b_hh[w*HH + j];
        }
        xch[bi][w][lane] = g;
    }
    __syncthreads();

    #pragma unroll
    for (int r=0; r<2; ++r){
        int bi = (w<<1) + r;
        int b  = b0 + bi;
        size_t o = (size_t)b*HH + j;
        float gi = xch[bi][0][lane];
        float gf = xch[bi][1][lane];
        float gg = xch[bi][2][lane];
        float go = xch[bi][3][lane];
        float ce = mask[bi] ? c_state[o] : c1[o];
        float c2 = sigm(gf)*ce + sigm(gi)*tanhf(gg);
        float h2 = sigm(go)*tanhf(c2);
        float he = mask[bi] ? hs_r[o] : h1_r[o];
        c_state[o] = ce;      // committed c through t-1
        c1[o]      = c2;      // tentative c of step t
        hs_w[o]    = he;      // committed h through t-1 (next step's read buffer)
        h1_w[o]    = h2;      // tentative h of step t
    }

    if (jt == 0 && t > 0 && threadIdx.x < 8){
        int bi = threadIdx.x; int b = b0 + bi;
        out_emit[(size_t)b*TT + (t-1)] = mask[bi] ? 0.0f : (float)kprev[bi];
        label[b] = sel[bi];   // idempotent-select race-safe
    }
}

// ---------------- P2: joint = relu(enc + h1@Wpred.T + b_pred) ----------------
template<int HAS_ENC>
__global__ __launch_bounds__(128) void k_p2(
    const float* __restrict__ Wpred,
    const float* __restrict__ Wenc,
    const float* __restrict__ x,
    const float* __restrict__ encproj,
    const float* __restrict__ b_enc,
    const float* __restrict__ b_pred,
    const float* __restrict__ h1,
    float* __restrict__ joint,
    unsigned long long* __restrict__ slot,
    int t)
{
    int tile = xcd_tile(blockIdx.x, 20);   // 160 tiles = 5 nt x 32 bg
    int nt = tile / 32;
    int bg = tile % 32;
    int lane = threadIdx.x & 63, w = threadIdx.x >> 6;
    int n  = nt*128 + w*64 + lane;
    int b0 = bg*4;

    float acc[4] = {0.f,0.f,0.f,0.f};
    const float* wr  = Wpred + (size_t)n*HH;
    const float* wr2 = Wenc  + (size_t)n*HH;

    for (int kc=0; kc<HH; kc+=16){
        float wv[16];
        #pragma unroll
        for (int q=0;q<4;q++){
            float4 f = *reinterpret_cast<const float4*>(wr + kc + q*4);
            wv[q*4+0]=f.x; wv[q*4+1]=f.y; wv[q*4+2]=f.z; wv[q*4+3]=f.w;
        }
        float wv2[16];
        if (!HAS_ENC){
            #pragma unroll
            for (int q=0;q<4;q++){
                float4 f = *reinterpret_cast<const float4*>(wr2 + kc + q*4);
                wv2[q*4+0]=f.x; wv2[q*4+1]=f.y; wv2[q*4+2]=f.z; wv2[q*4+3]=f.w;
            }
        }
        #pragma unroll
        for (int bi=0; bi<4; ++bi){
            int b = b0+bi;
            const float* hp = h1 + (size_t)b*HH + kc;
            float a = acc[bi];
            #pragma unroll
            for (int k=0;k<16;k++) a = fmaf(hp[k], wv[k], a);
            if (!HAS_ENC){
                const float* xp = x + (size_t)b*HH*TT + (size_t)kc*TT + t;
                #pragma unroll
                for (int k=0;k<16;k++) a = fmaf(xp[(size_t)k*TT], wv2[k], a);
            }
            acc[bi] = a;
        }
    }
    #pragma unroll
    for (int bi=0; bi<4; ++bi){
        int b = b0+bi;
        float v = acc[bi] + b_pred[n];
        if (HAS_ENC) v += encproj[(size_t)t*BB*HH + (size_t)b*HH + n];
        else         v += b_enc[n];
        joint[(size_t)b*HH + n] = fmaxf(v, 0.0f);
    }
    if (tile == 0) slot[threadIdx.x] = 0ULL;   // 128 threads reset 128 slots (safe: P1 already consumed)
}

// ---------------- P3: logits + argmax ----------------
__global__ __launch_bounds__(256) void k_p3(
    const float* __restrict__ Wout,
    const float* __restrict__ b_out,
    const float* __restrict__ joint,
    unsigned long long* __restrict__ slot)
{
    int tile = xcd_tile(blockIdx.x, 34);    // 272 tiles = 17 vt x 16 bg
    int vt = tile >> 4;
    int bg = tile & 15;
    int lane = threadIdx.x & 63, w = threadIdx.x >> 6;
    int v = vt*256 + w*64 + lane;
    bool valid = v < VV;
    int vv = valid ? v : (VV-1);
    int b0 = bg*8;

    float acc[8];
    #pragma unroll
    for (int i=0;i<8;i++) acc[i]=0.f;
    const float* wr = Wout + (size_t)vv*HH;

    for (int kc=0; kc<HH; kc+=16){
        float wv[16];
        #pragma unroll
        for (int q=0;q<4;q++){
            float4 f = *reinterpret_cast<const float4*>(wr + kc + q*4);
            wv[q*4+0]=f.x; wv[q*4+1]=f.y; wv[q*4+2]=f.z; wv[q*4+3]=f.w;
        }
        #pragma unroll
        for (int bi=0; bi<8; ++bi){
            int b = b0+bi;
            const float* jp = joint + (size_t)b*HH + kc;
            float a = acc[bi];
            #pragma unroll
            for (int k=0;k<16;k++) a = fmaf(jp[k], wv[k], a);
            acc[bi] = a;
        }
    }
    float bo = b_out[vv];
    __shared__ unsigned long long red[4][8];
    #pragma unroll
    for (int bi=0; bi<8; ++bi){
        unsigned long long key = valid ? packkey(acc[bi] + bo, (unsigned)v) : 0ULL;
        #pragma unroll
        for (int off=32; off>0; off>>=1){
            unsigned long long o = __shfl_xor(key, off, 64);
            if (o > key) key = o;
        }
        if (lane == 0) red[w][bi] = key;
    }
    __syncthreads();
    if (threadIdx.x < 8){
        int bi = threadIdx.x;
        unsigned long long m = red[0][bi];
        #pragma unroll
        for (int q=1;q<4;q++) if (red[q][bi] > m) m = red[q][bi];
        atomicMax(&slot[b0+bi], m);
    }
}

// ---------------- final: emit t=511, hF, cF ----------------
__global__ __launch_bounds__(256) void k_final(const int* __restrict__ lens,
                        const unsigned long long* __restrict__ slot,
                        const float* __restrict__ hs_r, const float* __restrict__ h1_r,
                        const float* __restrict__ cs,  const float* __restrict__ c1,
                        float* __restrict__ dout)
{
    int i = blockIdx.x*256 + threadIdx.x;
    if (i >= BB*HH) return;
    int b = i / HH;
    unsigned long long key = slot[b];
    int k = (int)(~(unsigned)key);
    bool m = ((TT-1) >= lens[b]) || (k == 0);
    dout[BB*TT + i]         = m ? hs_r[i] : h1_r[i];
    dout[BB*TT + BB*HH + i] = m ? cs[i]   : c1[i];
    if (i < BB){
        unsigned long long key2 = slot[i];
        int k2 = (int)(~(unsigned)key2);
        bool mm = ((TT-1) >= lens[i]) || (k2 == 0);
        dout[(size_t)i*TT + (TT-1)] = mm ? 0.0f : (float)k2;
    }
}

extern "C" void kernel_launch(void* const* d_in, const int* in_sizes, int n_in,
                              void* d_out, int out_size, void* d_ws, size_t ws_size,
                              hipStream_t stream)
{
    const float* x     = (const float*)d_in[0];
    const int*   lens  = (const int*)  d_in[1];
    const float* emb   = (const float*)d_in[2];
    const float* Wih   = (const float*)d_in[3];
    const float* Whh   = (const float*)d_in[4];
    const float* bih   = (const float*)d_in[5];
    const float* bhh   = (const float*)d_in[6];
    const float* Wenc  = (const float*)d_in[7];
    const float* benc  = (const float*)d_in[8];
    const float* Wpred = (const float*)d_in[9];
    const float* bpred = (const float*)d_in[10];
    const float* Wout  = (const float*)d_in[11];
    const float* bout  = (const float*)d_in[12];
    const float* h0    = (const float*)d_in[13];
    const float* c0    = (const float*)d_in[14];
    float* out = (float*)d_out;
    (void)in_sizes; (void)n_in; (void)out_size;

    char* ws = (char*)d_ws;
    size_t off = 0;
    auto alloc = [&](size_t bytes) -> void* {
        void* p = ws + off; off += (bytes + 255) & ~(size_t)255; return p;
    };
    const size_t BH = (size_t)BB*HH*sizeof(float);
    float* hs0  = (float*)alloc(BH);
    float* hs1  = (float*)alloc(BH);
    float* h1b0 = (float*)alloc(BH);
    float* h1b1 = (float*)alloc(BH);
    float* cs   = (float*)alloc(BH);
    float* c1   = (float*)alloc(BH);
    float* joint= (float*)alloc(BH);
    int* label  = (int*)alloc(BB*sizeof(int));
    unsigned long long* slot = (unsigned long long*)alloc(BB*sizeof(unsigned long long));

    float* embproj = nullptr; float* encproj = nullptr;
    bool hasEmb = false, hasEnc = false;
    size_t embBytes = (size_t)(VV+1)*G4*sizeof(float);
    size_t encBytes = (size_t)TT*BB*HH*sizeof(float);
    if (ws_size >= off + embBytes + 256){ embproj = (float*)alloc(embBytes); hasEmb = true; }
    if (hasEmb && ws_size >= off + encBytes + 256){ encproj = (float*)alloc(encBytes); hasEnc = true; }

    k_init<<<(BB*HH+255)/256, 256, 0, stream>>>(h0, c0, hs0, cs, label, slot);
    if (hasEmb) k_embproj<<<2576, 256, 0, stream>>>(emb, Wih, bih, bhh, embproj);
    if (hasEnc) k_encproj<<<20480, 128, 0, stream>>>(x, Wenc, benc, encproj);

    float* hsbuf[2] = {hs0, hs1};
    float* h1buf[2] = {h1b0, h1b1};

    for (int t = 0; t < TT; ++t){
        const float* hsr = hsbuf[t & 1];
        float*       hsw = hsbuf[(t+1) & 1];
        const float* h1r = h1buf[(t+1) & 1];
        float*       h1w = h1buf[t & 1];
        if (hasEmb)
            k_p1<1><<<160, 256, 0, stream>>>(Whh, Wih, embproj, emb, bih, bhh, lens,
                                             hsr, hsw, h1r, h1w, cs, c1, label, slot, out, t);
        else
            k_p1<0><<<160, 256, 0, stream>>>(Whh, Wih, embproj, emb, bih, bhh, lens,
                                             hsr, hsw, h1r, h1w, cs, c1, label, slot, out, t);
        if (hasEnc)
            k_p2<1><<<160, 128, 0, stream>>>(Wpred, Wenc, x, encproj, benc, bpred, h1w, joint, slot, t);
        else
            k_p2<0><<<160, 128, 0, stream>>>(Wpred, Wenc, x, encproj, benc, bpred, h1w, joint, slot, t);
        k_p3<<<272, 256, 0, stream>>>(Wout, bout, joint, slot);
    }
    k_final<<<(BB*HH+255)/256, 256, 0, stream>>>(lens, slot, hsbuf[0], h1buf[1], cs, c1, out);
}

// Round 2
// 37661.810 us; speedup vs baseline: 2.4453x; 2.4453x over previous
//
#include <hip/hip_runtime.h>
#include <stdint.h>

#define HH 640
#define BB 128
#define TT 512
#define VV 4097
#define G4 2560   // 4*HH
#define VP 4352   // padded Wout width (17*256)

__device__ __forceinline__ float sigm(float x){ return 1.0f/(1.0f+expf(-x)); }

// monotonic packed key: larger logit wins; ties -> smaller v (jnp.argmax first-index)
__device__ __forceinline__ unsigned long long packkey(float f, unsigned v){
    unsigned u = __float_as_uint(f);
    unsigned m = (u & 0x80000000u) ? ~u : (u | 0x80000000u);
    return ((unsigned long long)m << 32) | (unsigned long long)(~v);
}

// bijective XCD partition
__device__ __forceinline__ int xcd_tile(int bid, int per){ return (bid & 7)*per + (bid >> 3); }

// ---------------- init ----------------
__global__ __launch_bounds__(256) void k_init(const float* __restrict__ h0, const float* __restrict__ c0,
                       float* __restrict__ hs0, float* __restrict__ cs,
                       int* __restrict__ label, unsigned long long* __restrict__ slot){
    int i = blockIdx.x*256 + threadIdx.x;
    if (i < BB*HH){ hs0[i] = h0[i]; cs[i] = c0[i]; }
    if (i < BB){ label[i] = 0; slot[i] = 0ULL; }
}

// ---------------- one-time transposes ----------------
// gate-interleaved: WT[k][jj*4+g] = W[(g*HH+jj)*HH + k]
__global__ __launch_bounds__(256) void k_tr_gate(const float* __restrict__ W, float* __restrict__ WT){
    int idx = blockIdx.x*256 + threadIdx.x;   // 2560*160
    if (idx >= G4*160) return;
    int row = idx / 160, kq = idx % 160;
    int g = row / HH, jj = row % HH;
    float4 f = *reinterpret_cast<const float4*>(W + (size_t)row*HH + kq*4);
    WT[(size_t)(kq*4+0)*G4 + jj*4+g] = f.x;
    WT[(size_t)(kq*4+1)*G4 + jj*4+g] = f.y;
    WT[(size_t)(kq*4+2)*G4 + jj*4+g] = f.z;
    WT[(size_t)(kq*4+3)*G4 + jj*4+g] = f.w;
}
// WT[k][n] = W[n*HH+k], 640x640
__global__ __launch_bounds__(256) void k_tr640(const float* __restrict__ W, float* __restrict__ WT){
    int idx = blockIdx.x*256 + threadIdx.x;   // 640*160
    if (idx >= HH*160) return;
    int n = idx / 160, kq = idx % 160;
    float4 f = *reinterpret_cast<const float4*>(W + (size_t)n*HH + kq*4);
    WT[(size_t)(kq*4+0)*HH + n] = f.x;
    WT[(size_t)(kq*4+1)*HH + n] = f.y;
    WT[(size_t)(kq*4+2)*HH + n] = f.z;
    WT[(size_t)(kq*4+3)*HH + n] = f.w;
}
// WoutT[k][v] padded to VP, zero pad
__global__ __launch_bounds__(256) void k_tr_wout(const float* __restrict__ W, float* __restrict__ WT){
    int idx = blockIdx.x*256 + threadIdx.x;   // VP*160
    if (idx >= VP*160) return;
    int v = idx / 160, kq = idx % 160;
    float4 f = make_float4(0.f,0.f,0.f,0.f);
    if (v < VV) f = *reinterpret_cast<const float4*>(W + (size_t)v*HH + kq*4);
    WT[(size_t)(kq*4+0)*VP + v] = f.x;
    WT[(size_t)(kq*4+1)*VP + v] = f.y;
    WT[(size_t)(kq*4+2)*VP + v] = f.z;
    WT[(size_t)(kq*4+3)*VP + v] = f.w;
}

// ---------------- emb_proj precompute: [VV+1][2560] gate-interleaved; row VV = bias-only ----------------
__global__ __launch_bounds__(256) void k_embproj(const float* __restrict__ embedding,
                          const float* __restrict__ Wih,
                          const float* __restrict__ b_ih, const float* __restrict__ b_hh,
                          float* __restrict__ embproj){
    int tile = xcd_tile(blockIdx.x, 322);
    if (tile >= 2570) return;
    int ut = tile / 257;
    int vg = tile % 257;
    int u  = ut*256 + threadIdx.x;
    float acc[16];
    #pragma unroll
    for (int i=0;i<16;i++) acc[i]=0.f;
    const float* wr = Wih + (size_t)u*HH;
    for (int kc=0; kc<HH; kc+=16){
        float wv[16];
        #pragma unroll
        for (int q=0;q<4;q++){
            float4 f = *reinterpret_cast<const float4*>(wr + kc + q*4);
            wv[q*4+0]=f.x; wv[q*4+1]=f.y; wv[q*4+2]=f.z; wv[q*4+3]=f.w;
        }
        #pragma unroll
        for (int vi=0; vi<16; ++vi){
            int v = vg*16+vi;
            if (v < VV){
                const float* ep = embedding + (size_t)v*HH + kc;
                float a = acc[vi];
                #pragma unroll
                for (int k=0;k<16;k++) a = fmaf(ep[k], wv[k], a);
                acc[vi] = a;
            }
        }
    }
    float bias = b_ih[u] + b_hh[u];
    int g = u / HH, jj = u % HH;
    #pragma unroll
    for (int vi=0; vi<16; ++vi){
        int v = vg*16+vi;
        if (v <= VV) embproj[(size_t)v*G4 + jj*4 + g] = acc[vi] + bias;
    }
}

// ---------------- enc_proj precompute ----------------
__global__ __launch_bounds__(128) void k_encproj(const float* __restrict__ x,
                          const float* __restrict__ Wenc, const float* __restrict__ b_enc,
                          float* __restrict__ encproj){
    int tile = xcd_tile(blockIdx.x, 2560);
    int b   = tile / 160;
    int rem = tile % 160;
    int tt  = rem / 5;
    int nt2 = rem % 5;
    int lane = threadIdx.x & 63, w = threadIdx.x >> 6;
    int n = nt2*128 + w*64 + lane;
    float acc[16];
    #pragma unroll
    for (int i=0;i<16;i++) acc[i]=0.f;
    const float* wr = Wenc + (size_t)n*HH;
    for (int kc=0; kc<HH; kc+=16){
        float wv[16];
        #pragma unroll
        for (int q=0;q<4;q++){
            float4 f = *reinterpret_cast<const float4*>(wr + kc + q*4);
            wv[q*4+0]=f.x; wv[q*4+1]=f.y; wv[q*4+2]=f.z; wv[q*4+3]=f.w;
        }
        #pragma unroll
        for (int k=0;k<16;k++){
            const float* xp = x + (size_t)b*HH*TT + (size_t)(kc+k)*TT + tt*16;
            float ww = wv[k];
            #pragma unroll
            for (int ti=0; ti<16; ++ti) acc[ti] = fmaf(xp[ti], ww, acc[ti]);
        }
    }
    float be = b_enc[n];
    #pragma unroll
    for (int ti=0; ti<16; ++ti)
        encproj[(size_t)(tt*16+ti)*BB*HH + (size_t)b*HH + n] = acc[ti] + be;
}

// ---------------- NEW P1: coalesced WhhT/WihT, waves split K, LDS reduce ----------------
template<int HAS_EMB>
__global__ __launch_bounds__(256) void k_p1n(
    const float* __restrict__ WhhT,
    const float* __restrict__ WihT,
    const float* __restrict__ embproj,
    const float* __restrict__ embedding,
    const float* __restrict__ b_ih, const float* __restrict__ b_hh,
    const int* __restrict__ lens,
    const float* __restrict__ hs_r, float* __restrict__ hs_w,
    const float* __restrict__ h1_r, float* __restrict__ h1_w,
    float* __restrict__ c_state, float* __restrict__ c1,
    int* __restrict__ label,
    const unsigned long long* __restrict__ slot,
    float* __restrict__ out_emit, int t)
{
    int tile = xcd_tile(blockIdx.x, 20);   // 160 = 10 jt x 16 bg
    int jt = tile / 16, bg = tile & 15;
    int l = threadIdx.x & 63, w = threadIdx.x >> 6;
    int b0 = bg << 3;
    int jj = jt*64 + l;

    bool mask[8]; int kprev[8]; int sel[8];
    #pragma unroll
    for (int bi=0; bi<8; ++bi){
        int b = b0+bi;
        if (t == 0){ mask[bi]=true; sel[bi]=0; kprev[bi]=0; }
        else {
            unsigned long long key = slot[b];
            int k = (int)(~(unsigned)key);
            int lab = label[b];
            bool m = ((t-1) >= lens[b]) || (k == 0);
            mask[bi]=m; kprev[bi]=k; sel[bi] = m ? lab : k;
        }
    }
    const float* hp[8];
    #pragma unroll
    for (int bi=0; bi<8; ++bi)
        hp[bi] = (mask[bi] ? hs_r : h1_r) + (size_t)(b0+bi)*HH + w*160;

    float acc[4][8];
    #pragma unroll
    for (int g=0; g<4; ++g)
        #pragma unroll
        for (int bi=0; bi<8; ++bi) acc[g][bi]=0.f;

    const float* wb  = WhhT + (size_t)(w*160)*G4 + jj*4;
    const float* wb2 = WihT + (size_t)(w*160)*G4 + jj*4;

    for (int kk=0; kk<160; kk+=4){
        float4 hv[8];
        #pragma unroll
        for (int bi=0; bi<8; ++bi)
            hv[bi] = *reinterpret_cast<const float4*>(hp[bi] + kk);
        #pragma unroll
        for (int q=0; q<4; ++q){
            float4 wv = *reinterpret_cast<const float4*>(wb + (size_t)(kk+q)*G4);
            #pragma unroll
            for (int bi=0; bi<8; ++bi){
                float h = q==0?hv[bi].x: q==1?hv[bi].y: q==2?hv[bi].z: hv[bi].w;
                acc[0][bi]=fmaf(wv.x,h,acc[0][bi]);
                acc[1][bi]=fmaf(wv.y,h,acc[1][bi]);
                acc[2][bi]=fmaf(wv.z,h,acc[2][bi]);
                acc[3][bi]=fmaf(wv.w,h,acc[3][bi]);
            }
        }
        if (!HAS_EMB){
            if (t > 0){
                #pragma unroll
                for (int q=0; q<4; ++q){
                    float4 wv2 = *reinterpret_cast<const float4*>(wb2 + (size_t)(kk+q)*G4);
                    #pragma unroll
                    for (int bi=0; bi<8; ++bi){
                        float e = embedding[(size_t)sel[bi]*HH + w*160 + kk + q];
                        acc[0][bi]=fmaf(wv2.x,e,acc[0][bi]);
                        acc[1][bi]=fmaf(wv2.y,e,acc[1][bi]);
                        acc[2][bi]=fmaf(wv2.z,e,acc[2][bi]);
                        acc[3][bi]=fmaf(wv2.w,e,acc[3][bi]);
                    }
                }
            }
        }
    }
    __shared__ float red[4][32][64];
    #pragma unroll
    for (int g=0; g<4; ++g)
        #pragma unroll
        for (int bi=0; bi<8; ++bi)
            red[w][g*8+bi][l] = acc[g][bi];
    __syncthreads();

    float bsum[4];
    if (!HAS_EMB){
        #pragma unroll
        for (int g=0; g<4; ++g) bsum[g] = b_ih[g*HH+jj] + b_hh[g*HH+jj];
    }
    #pragma unroll
    for (int r=0; r<2; ++r){
        int bi = w*2 + r;
        float gg4[4];
        #pragma unroll
        for (int g=0; g<4; ++g)
            gg4[g] = red[0][g*8+bi][l]+red[1][g*8+bi][l]+red[2][g*8+bi][l]+red[3][g*8+bi][l];
        if (HAS_EMB){
            int row = (t==0) ? VV : sel[bi];
            float4 e = *reinterpret_cast<const float4*>(embproj + (size_t)row*G4 + jj*4);
            gg4[0]+=e.x; gg4[1]+=e.y; gg4[2]+=e.z; gg4[3]+=e.w;
        } else {
            #pragma unroll
            for (int g=0; g<4; ++g) gg4[g]+=bsum[g];
        }
        size_t o = (size_t)(b0+bi)*HH + jj;
        float ce = mask[bi] ? c_state[o] : c1[o];
        float c2v = sigm(gg4[1])*ce + sigm(gg4[0])*tanhf(gg4[2]);
        float h2 = sigm(gg4[3])*tanhf(c2v);
        float he = mask[bi] ? hs_r[o] : h1_r[o];
        c_state[o]=ce; c1[o]=c2v; hs_w[o]=he; h1_w[o]=h2;
    }
    if (jt==0 && t>0 && threadIdx.x<8){
        int bi=threadIdx.x; int b=b0+bi;
        out_emit[(size_t)b*TT + (t-1)] = mask[bi]?0.0f:(float)kprev[bi];
        label[b] = sel[bi];
    }
}

// ---------------- NEW P2 ----------------
template<int HAS_ENC>
__global__ __launch_bounds__(256) void k_p2n(
    const float* __restrict__ WpredT,
    const float* __restrict__ WencT,
    const float* __restrict__ x,
    const float* __restrict__ encproj,
    const float* __restrict__ b_enc,
    const float* __restrict__ b_pred,
    const float* __restrict__ h1,
    float* __restrict__ joint,
    unsigned long long* __restrict__ slot,
    int t)
{
    int tile = xcd_tile(blockIdx.x, 20);   // 160 = 5 nt x 32 bg
    int nt = tile / 32, bg = tile % 32;
    int l = threadIdx.x & 63, w = threadIdx.x >> 6;
    int b0 = bg*4;
    int n0 = nt*128 + l*2;
    float acc[2][4];
    #pragma unroll
    for (int ni=0;ni<2;++ni)
        #pragma unroll
        for (int bi=0;bi<4;++bi) acc[ni][bi]=0.f;
    const float* wb = WpredT + (size_t)(w*160)*HH + n0;
    const float* eb = WencT  + (size_t)(w*160)*HH + n0;
    const float* hb[4];
    #pragma unroll
    for (int bi=0; bi<4; ++bi) hb[bi] = h1 + (size_t)(b0+bi)*HH + w*160;

    for (int kk=0; kk<160; kk+=4){
        float4 hv[4];
        #pragma unroll
        for (int bi=0; bi<4; ++bi) hv[bi] = *reinterpret_cast<const float4*>(hb[bi]+kk);
        float xv[4][4];
        if (!HAS_ENC){
            #pragma unroll
            for (int bi=0; bi<4; ++bi)
                #pragma unroll
                for (int q=0; q<4; ++q)
                    xv[bi][q] = x[(size_t)(b0+bi)*HH*TT + (size_t)(w*160+kk+q)*TT + t];
        }
        #pragma unroll
        for (int q=0; q<4; ++q){
            float2 wv = *reinterpret_cast<const float2*>(wb + (size_t)(kk+q)*HH);
            float2 ev = make_float2(0.f,0.f);
            if (!HAS_ENC) ev = *reinterpret_cast<const float2*>(eb + (size_t)(kk+q)*HH);
            #pragma unroll
            for (int bi=0; bi<4; ++bi){
                float h = q==0?hv[bi].x:q==1?hv[bi].y:q==2?hv[bi].z:hv[bi].w;
                acc[0][bi]=fmaf(wv.x,h,acc[0][bi]);
                acc[1][bi]=fmaf(wv.y,h,acc[1][bi]);
                if (!HAS_ENC){
                    acc[0][bi]=fmaf(ev.x,xv[bi][q],acc[0][bi]);
                    acc[1][bi]=fmaf(ev.y,xv[bi][q],acc[1][bi]);
                }
            }
        }
    }
    __shared__ float red2[4][8][64];
    #pragma unroll
    for (int ni=0; ni<2; ++ni)
        #pragma unroll
        for (int bi=0; bi<4; ++bi)
            red2[w][bi*2+ni][l] = acc[ni][bi];
    __syncthreads();
    #pragma unroll
    for (int pp=0; pp<2; ++pp){
        int p = threadIdx.x + pp*256;
        int b = p >> 7, nidx = p & 127;
        int n = nt*128 + nidx;
        int c = b*2 + (nidx&1), r = nidx>>1;
        float s = red2[0][c][r]+red2[1][c][r]+red2[2][c][r]+red2[3][c][r];
        s += b_pred[n];
        if (HAS_ENC) s += encproj[(size_t)t*BB*HH + (size_t)(b0+b)*HH + n];
        else         s += b_enc[n];
        joint[(size_t)(b0+b)*HH + n] = fmaxf(s, 0.f);
    }
    if (tile==0 && threadIdx.x<BB) slot[threadIdx.x]=0ULL;
}

// ---------------- NEW P3 ----------------
__global__ __launch_bounds__(256) void k_p3n(
    const float* __restrict__ WoutT,
    const float* __restrict__ b_out,
    const float* __restrict__ joint,
    unsigned long long* __restrict__ slot)
{
    int tile = xcd_tile(blockIdx.x, 34);   // 272 = 17 vt x 16 bg
    int vt = tile / 16, bg = tile & 15;
    int l = threadIdx.x & 63, w = threadIdx.x >> 6;
    int b0 = bg << 3;
    int v0 = vt*256 + l*4;
    float acc[4][8];
    #pragma unroll
    for (int vi=0;vi<4;++vi)
        #pragma unroll
        for (int bi=0;bi<8;++bi) acc[vi][bi]=0.f;
    const float* wb = WoutT + (size_t)(w*160)*VP + v0;
    const float* jb[8];
    #pragma unroll
    for (int bi=0;bi<8;++bi) jb[bi] = joint + (size_t)(b0+bi)*HH + w*160;
    for (int kk=0; kk<160; kk+=4){
        float4 hv[8];
        #pragma unroll
        for (int bi=0;bi<8;++bi) hv[bi] = *reinterpret_cast<const float4*>(jb[bi]+kk);
        #pragma unroll
        for (int q=0;q<4;++q){
            float4 wv = *reinterpret_cast<const float4*>(wb + (size_t)(kk+q)*VP);
            #pragma unroll
            for (int bi=0;bi<8;++bi){
                float h = q==0?hv[bi].x:q==1?hv[bi].y:q==2?hv[bi].z:hv[bi].w;
                acc[0][bi]=fmaf(wv.x,h,acc[0][bi]);
                acc[1][bi]=fmaf(wv.y,h,acc[1][bi]);
                acc[2][bi]=fmaf(wv.z,h,acc[2][bi]);
                acc[3][bi]=fmaf(wv.w,h,acc[3][bi]);
            }
        }
    }
    __shared__ float red[4][32][64];
    #pragma unroll
    for (int vi=0;vi<4;++vi)
        #pragma unroll
        for (int bi=0;bi<8;++bi)
            red[w][bi*4+vi][l] = acc[vi][bi];
    __syncthreads();
    #pragma unroll
    for (int r=0;r<2;++r){
        int bi = w*2+r;
        unsigned long long key = 0ULL;
        #pragma unroll
        for (int vi=0;vi<4;++vi){
            float s = red[0][bi*4+vi][l]+red[1][bi*4+vi][l]+red[2][bi*4+vi][l]+red[3][bi*4+vi][l];
            int v = vt*256 + l*4 + vi;
            if (v < VV){
                unsigned long long kk2 = packkey(s + b_out[v], (unsigned)v);
                if (kk2 > key) key = kk2;
            }
        }
        #pragma unroll
        for (int off=32; off>0; off>>=1){
            unsigned long long o = __shfl_xor(key, off, 64);
            if (o > key) key = o;
        }
        if (l==0) atomicMax(&slot[b0+bi], key);
    }
}

// ---------------- OLD kernels kept as tier0 fallback ----------------
template<int HAS_EMB>
__global__ __launch_bounds__(256) void k_p1(
    const float* __restrict__ Whh, const float* __restrict__ Wih,
    const float* __restrict__ embproj, const float* __restrict__ embedding,
    const float* __restrict__ b_ih, const float* __restrict__ b_hh,
    const int* __restrict__ lens,
    const float* __restrict__ hs_r, float* __restrict__ hs_w,
    const float* __restrict__ h1_r, float* __restrict__ h1_w,
    float* c_state, float* c1, int* label,
    const unsigned long long* __restrict__ slot,
    float* __restrict__ out_emit, int t)
{
    int tile = xcd_tile(blockIdx.x, 20);
    int jt = tile >> 4;
    int bg = tile & 15;
    int lane = threadIdx.x & 63;
    int w    = threadIdx.x >> 6;
    int j  = (jt<<6) + lane;
    int b0 = bg<<3;

    bool mask[8]; int kprev[8]; int sel[8];
    #pragma unroll
    for (int bi=0; bi<8; ++bi){
        int b = b0+bi;
        if (t == 0){ mask[bi]=true; sel[bi]=0; kprev[bi]=0; }
        else {
            unsigned long long key = slot[b];
            int k = (int)(~(unsigned)key);
            int lab = label[b];
            bool m = ((t-1) >= lens[b]) || (k == 0);
            mask[bi]=m; kprev[bi]=k; sel[bi] = m ? lab : k;
        }
    }
    float acc[8];
    #pragma unroll
    for (int i=0;i<8;i++) acc[i]=0.f;
    const float* wrow  = Whh + (size_t)(w*HH + j)*HH;
    const float* wrow2 = Wih + (size_t)(w*HH + j)*HH;
    for (int kc=0; kc<HH; kc+=16){
        float wv[16];
        #pragma unroll
        for (int q=0;q<4;q++){
            float4 f = *reinterpret_cast<const float4*>(wrow + kc + q*4);
            wv[q*4+0]=f.x; wv[q*4+1]=f.y; wv[q*4+2]=f.z; wv[q*4+3]=f.w;
        }
        float wv2[16];
        if (!HAS_EMB){
            #pragma unroll
            for (int q=0;q<4;q++){
                float4 f = *reinterpret_cast<const float4*>(wrow2 + kc + q*4);
                wv2[q*4+0]=f.x; wv2[q*4+1]=f.y; wv2[q*4+2]=f.z; wv2[q*4+3]=f.w;
            }
        }
        #pragma unroll
        for (int bi=0; bi<8; ++bi){
            int b = b0+bi;
            const float* hp0 = hs_r + (size_t)b*HH + kc;
            const float* hp1 = h1_r + (size_t)b*HH + kc;
            float a = acc[bi];
            if (mask[bi]){
                #pragma unroll
                for (int k=0;k<16;k++) a = fmaf(hp0[k], wv[k], a);
            } else {
                #pragma unroll
                for (int k=0;k<16;k++) a = fmaf(hp1[k], wv[k], a);
            }
            if (!HAS_EMB){
                if (t > 0){
                    const float* ep = embedding + (size_t)sel[bi]*HH + kc;
                    #pragma unroll
                    for (int k=0;k<16;k++) a = fmaf(ep[k], wv2[k], a);
                }
            }
            acc[bi] = a;
        }
    }
    __shared__ float xch[8][4][64];
    #pragma unroll
    for (int bi=0; bi<8; ++bi){
        float g = acc[bi];
        g += b_ih[w*HH + j] + b_hh[w*HH + j];
        xch[bi][w][lane] = g;
    }
    __syncthreads();
    #pragma unroll
    for (int r=0; r<2; ++r){
        int bi = (w<<1) + r;
        int b  = b0 + bi;
        size_t o = (size_t)b*HH + j;
        float gi = xch[bi][0][lane];
        float gf = xch[bi][1][lane];
        float gg = xch[bi][2][lane];
        float go = xch[bi][3][lane];
        float ce = mask[bi] ? c_state[o] : c1[o];
        float c2 = sigm(gf)*ce + sigm(gi)*tanhf(gg);
        float h2 = sigm(go)*tanhf(c2);
        float he = mask[bi] ? hs_r[o] : h1_r[o];
        c_state[o] = ce; c1[o] = c2; hs_w[o] = he; h1_w[o] = h2;
    }
    if (jt == 0 && t > 0 && threadIdx.x < 8){
        int bi = threadIdx.x; int b = b0 + bi;
        out_emit[(size_t)b*TT + (t-1)] = mask[bi] ? 0.0f : (float)kprev[bi];
        label[b] = sel[bi];
    }
}

__global__ __launch_bounds__(128) void k_p2o(
    const float* __restrict__ Wpred, const float* __restrict__ Wenc,
    const float* __restrict__ x, const float* __restrict__ b_enc,
    const float* __restrict__ b_pred, const float* __restrict__ h1,
    float* __restrict__ joint, unsigned long long* __restrict__ slot, int t)
{
    int tile = xcd_tile(blockIdx.x, 20);
    int nt = tile / 32;
    int bg = tile % 32;
    int lane = threadIdx.x & 63, w = threadIdx.x >> 6;
    int n  = nt*128 + w*64 + lane;
    int b0 = bg*4;
    float acc[4] = {0.f,0.f,0.f,0.f};
    const float* wr  = Wpred + (size_t)n*HH;
    const float* wr2 = Wenc  + (size_t)n*HH;
    for (int kc=0; kc<HH; kc+=16){
        float wv[16];
        #pragma unroll
        for (int q=0;q<4;q++){
            float4 f = *reinterpret_cast<const float4*>(wr + kc + q*4);
            wv[q*4+0]=f.x; wv[q*4+1]=f.y; wv[q*4+2]=f.z; wv[q*4+3]=f.w;
        }
        float wv2[16];
        #pragma unroll
        for (int q=0;q<4;q++){
            float4 f = *reinterpret_cast<const float4*>(wr2 + kc + q*4);
            wv2[q*4+0]=f.x; wv2[q*4+1]=f.y; wv2[q*4+2]=f.z; wv2[q*4+3]=f.w;
        }
        #pragma unroll
        for (int bi=0; bi<4; ++bi){
            int b = b0+bi;
            const float* hp = h1 + (size_t)b*HH + kc;
            float a = acc[bi];
            #pragma unroll
            for (int k=0;k<16;k++) a = fmaf(hp[k], wv[k], a);
            const float* xp = x + (size_t)b*HH*TT + (size_t)kc*TT + t;
            #pragma unroll
            for (int k=0;k<16;k++) a = fmaf(xp[(size_t)k*TT], wv2[k], a);
            acc[bi] = a;
        }
    }
    #pragma unroll
    for (int bi=0; bi<4; ++bi){
        int b = b0+bi;
        float v = acc[bi] + b_pred[n] + b_enc[n];
        joint[(size_t)b*HH + n] = fmaxf(v, 0.0f);
    }
    if (tile == 0) slot[threadIdx.x] = 0ULL;
}

__global__ __launch_bounds__(256) void k_p3(
    const float* __restrict__ Wout, const float* __restrict__ b_out,
    const float* __restrict__ joint, unsigned long long* __restrict__ slot)
{
    int tile = xcd_tile(blockIdx.x, 34);
    int vt = tile >> 4;
    int bg = tile & 15;
    int lane = threadIdx.x & 63, w = threadIdx.x >> 6;
    int v = vt*256 + w*64 + lane;
    bool valid = v < VV;
    int vv = valid ? v : (VV-1);
    int b0 = bg*8;
    float acc[8];
    #pragma unroll
    for (int i=0;i<8;i++) acc[i]=0.f;
    const float* wr = Wout + (size_t)vv*HH;
    for (int kc=0; kc<HH; kc+=16){
        float wv[16];
        #pragma unroll
        for (int q=0;q<4;q++){
            float4 f = *reinterpret_cast<const float4*>(wr + kc + q*4);
            wv[q*4+0]=f.x; wv[q*4+1]=f.y; wv[q*4+2]=f.z; wv[q*4+3]=f.w;
        }
        #pragma unroll
        for (int bi=0; bi<8; ++bi){
            int b = b0+bi;
            const float* jp = joint + (size_t)b*HH + kc;
            float a = acc[bi];
            #pragma unroll
            for (int k=0;k<16;k++) a = fmaf(jp[k], wv[k], a);
            acc[bi] = a;
        }
    }
    float bo = b_out[vv];
    __shared__ unsigned long long redo[4][8];
    #pragma unroll
    for (int bi=0; bi<8; ++bi){
        unsigned long long key = valid ? packkey(acc[bi] + bo, (unsigned)v) : 0ULL;
        #pragma unroll
        for (int off=32; off>0; off>>=1){
            unsigned long long o = __shfl_xor(key, off, 64);
            if (o > key) key = o;
        }
        if (lane == 0) redo[w][bi] = key;
    }
    __syncthreads();
    if (threadIdx.x < 8){
        int bi = threadIdx.x;
        unsigned long long m = redo[0][bi];
        #pragma unroll
        for (int q=1;q<4;q++) if (redo[q][bi] > m) m = redo[q][bi];
        atomicMax(&slot[b0+bi], m);
    }
}

// ---------------- final ----------------
__global__ __launch_bounds__(256) void k_final(const int* __restrict__ lens,
                        const unsigned long long* __restrict__ slot,
                        const float* __restrict__ hs_r, const float* __restrict__ h1_r,
                        const float* __restrict__ cs,  const float* __restrict__ c1,
                        float* __restrict__ dout)
{
    int i = blockIdx.x*256 + threadIdx.x;
    if (i >= BB*HH) return;
    int b = i / HH;
    unsigned long long key = slot[b];
    int k = (int)(~(unsigned)key);
    bool m = ((TT-1) >= lens[b]) || (k == 0);
    dout[BB*TT + i]         = m ? hs_r[i] : h1_r[i];
    dout[BB*TT + BB*HH + i] = m ? cs[i]   : c1[i];
    if (i < BB){
        unsigned long long key2 = slot[i];
        int k2 = (int)(~(unsigned)key2);
        bool mm = ((TT-1) >= lens[i]) || (k2 == 0);
        dout[(size_t)i*TT + (TT-1)] = mm ? 0.0f : (float)k2;
    }
}

extern "C" void kernel_launch(void* const* d_in, const int* in_sizes, int n_in,
                              void* d_out, int out_size, void* d_ws, size_t ws_size,
                              hipStream_t stream)
{
    const float* x     = (const float*)d_in[0];
    const int*   lens  = (const int*)  d_in[1];
    const float* emb   = (const float*)d_in[2];
    const float* Wih   = (const float*)d_in[3];
    const float* Whh   = (const float*)d_in[4];
    const float* bih   = (const float*)d_in[5];
    const float* bhh   = (const float*)d_in[6];
    const float* Wenc  = (const float*)d_in[7];
    const float* benc  = (const float*)d_in[8];
    const float* Wpred = (const float*)d_in[9];
    const float* bpred = (const float*)d_in[10];
    const float* Wout  = (const float*)d_in[11];
    const float* bout  = (const float*)d_in[12];
    const float* h0    = (const float*)d_in[13];
    const float* c0    = (const float*)d_in[14];
    float* out = (float*)d_out;
    (void)in_sizes; (void)n_in; (void)out_size;

    char* ws = (char*)d_ws;
    size_t off = 0;
    auto alloc = [&](size_t bytes) -> void* {
        void* p = ws + off; off += (bytes + 255) & ~(size_t)255; return p;
    };
    const size_t BH = (size_t)BB*HH*sizeof(float);
    float* hs0  = (float*)alloc(BH);
    float* hs1  = (float*)alloc(BH);
    float* h1b0 = (float*)alloc(BH);
    float* h1b1 = (float*)alloc(BH);
    float* cs   = (float*)alloc(BH);
    float* c1   = (float*)alloc(BH);
    float* joint= (float*)alloc(BH);
    int* label  = (int*)alloc(BB*sizeof(int));
    unsigned long long* slot = (unsigned long long*)alloc(BB*sizeof(unsigned long long));

    // tier1: transposed weights
    float *WhhT=nullptr,*WihT=nullptr,*WpredT=nullptr,*WencT=nullptr,*WoutT=nullptr;
    bool hasTr=false;
    {
        size_t trBytes = ((size_t)HH*G4*2 + (size_t)HH*HH*2 + (size_t)HH*VP)*sizeof(float) + 5*256;
        if (ws_size >= off + trBytes){
            WhhT  = (float*)alloc((size_t)HH*G4*sizeof(float));
            WihT  = (float*)alloc((size_t)HH*G4*sizeof(float));
            WpredT= (float*)alloc((size_t)HH*HH*sizeof(float));
            WencT = (float*)alloc((size_t)HH*HH*sizeof(float));
            WoutT = (float*)alloc((size_t)HH*VP*sizeof(float));
            hasTr = true;
        }
    }
    // tier2: embproj; tier3: encproj
    float* embproj = nullptr; float* encproj = nullptr;
    bool hasEmb = false, hasEnc = false;
    size_t embBytes = (size_t)(VV+1)*G4*sizeof(float);
    size_t encBytes = (size_t)TT*BB*HH*sizeof(float);
    if (hasTr && ws_size >= off + embBytes + 256){ embproj = (float*)alloc(embBytes); hasEmb = true; }
    if (hasEmb && ws_size >= off + encBytes + 256){ encproj = (float*)alloc(encBytes); hasEnc = true; }

    k_init<<<(BB*HH+255)/256, 256, 0, stream>>>(h0, c0, hs0, cs, label, slot);
    if (hasTr){
        k_tr_gate<<<(G4*160+255)/256, 256, 0, stream>>>(Whh, WhhT);
        k_tr_gate<<<(G4*160+255)/256, 256, 0, stream>>>(Wih, WihT);
        k_tr640 <<<(HH*160+255)/256, 256, 0, stream>>>(Wpred, WpredT);
        k_tr640 <<<(HH*160+255)/256, 256, 0, stream>>>(Wenc,  WencT);
        k_tr_wout<<<(VP*160+255)/256, 256, 0, stream>>>(Wout, WoutT);
    }
    if (hasEmb) k_embproj<<<2576, 256, 0, stream>>>(emb, Wih, bih, bhh, embproj);
    if (hasEnc) k_encproj<<<20480, 128, 0, stream>>>(x, Wenc, benc, encproj);

    float* hsbuf[2] = {hs0, hs1};
    float* h1buf[2] = {h1b0, h1b1};

    for (int t = 0; t < TT; ++t){
        const float* hsr = hsbuf[t & 1];
        float*       hsw = hsbuf[(t+1) & 1];
        const float* h1r = h1buf[(t+1) & 1];
        float*       h1w = h1buf[t & 1];
        if (hasTr){
            if (hasEmb)
                k_p1n<1><<<160, 256, 0, stream>>>(WhhT, WihT, embproj, emb, bih, bhh, lens,
                                                  hsr, hsw, h1r, h1w, cs, c1, label, slot, out, t);
            else
                k_p1n<0><<<160, 256, 0, stream>>>(WhhT, WihT, embproj, emb, bih, bhh, lens,
                                                  hsr, hsw, h1r, h1w, cs, c1, label, slot, out, t);
            if (hasEnc)
                k_p2n<1><<<160, 256, 0, stream>>>(WpredT, WencT, x, encproj, benc, bpred, h1w, joint, slot, t);
            else
                k_p2n<0><<<160, 256, 0, stream>>>(WpredT, WencT, x, encproj, benc, bpred, h1w, joint, slot, t);
            k_p3n<<<272, 256, 0, stream>>>(WoutT, bout, joint, slot);
        } else {
            k_p1<0><<<160, 256, 0, stream>>>(Whh, Wih, embproj, emb, bih, bhh, lens,
                                             hsr, hsw, h1r, h1w, cs, c1, label, slot, out, t);
            k_p2o<<<160, 128, 0, stream>>>(Wpred, Wenc, x, benc, bpred, h1w, joint, slot, t);
            k_p3<<<272, 256, 0, stream>>>(Wout, bout, joint, slot);
        }
    }
    k_final<<<(BB*HH+255)/256, 256, 0, stream>>>(lens, slot, hsbuf[0], h1buf[1], cs, c1, out);
}